// Round 2
// baseline (65730.927 us; speedup 1.0000x reference)
//
#include <hip/hip_runtime.h>
#include <stdint.h>

// Problem sizes
#define Bz 32
#define Tz 512
#define Ez 768
#define Hz 512
#define G4 2048      // 4*H
#define KAM 2048     // A-matrix K: [ctx(768) | x_t(768) | h(512)]
#define NBLK 256
#define NSTEP 512

typedef __attribute__((ext_vector_type(8))) short short8;
typedef __attribute__((ext_vector_type(4))) float f32x4;

// ---------------- ws layout (bytes) ----------------
#define OFF_SUB    0u            // 32 sub-barrier counters, 64B padded = 2048
#define OFF_GRP    2048u         // 32 group counters, 64B padded = 2048 -> 4096
#define OFF_H32    4096u         // 2*32*512 f32 = 131072 -> 135168
#define OFF_CST    135168u       // 2*32*512 f32 = 131072 -> 266240
#define CTRL_BYTES 266240u       // memset-0 region
#define OFF_AMATH  266240u       // 64*2048 bf16 = 262144 -> 528384
#define OFF_AMATL  528384u       // 262144 -> 790528
#define OFF_DEC    790528u       // 2*32*512 f32 = 131072 -> 921600
#define OFF_PCTX   921600u       // 2*32*8*768 f32 = 1572864 -> 2494464
#define OFF_PSTAT  2494464u      // 2*32*8*2 f32 = 4096 -> 2498560
#define OFF_BIASG  2498560u      // 2*2048 f32 = 16384 -> 2514944
#define OFF_EMB16  2514944u      // 32*512*768 bf16 = 25165824 -> 27680768
#define OFF_EP32   27680768u     // 32*512*512 f32 = 33554432 -> 61235200
#define OFF_WIHHI  61235200u     // 2*2048*1536 bf16 = 12582912 -> 73818112
#define OFF_WIHLO  73818112u     // 12582912 -> 86401024
#define OFF_WHHHI  86401024u     // 2*2048*512 bf16 = 4194304 -> 90595328
#define OFF_WHHLO  90595328u     // 4194304 -> 94789632
// wenc hi/lo alias the scan-only amat/dec/pctx region (encgemm finishes first)
#define OFF_WENCHI OFF_AMATH
#define OFF_WENCLO (OFF_AMATH + 786432u)
#define WS_NEEDED  94789632u     // ~90.4 MiB

__device__ __forceinline__ float b2f(short s){
  union { unsigned int u; float f; } w;
  w.u = ((unsigned int)(unsigned short)s) << 16;
  return w.f;
}
__device__ __forceinline__ unsigned short f2b(float f){
  union { float f; unsigned int u; } w; w.f = f;
  unsigned int u = w.u;
  return (unsigned short)((u + 0x7fffu + ((u >> 16) & 1u)) >> 16);
}
__device__ __forceinline__ float fast_tanh(float x){
  float e = __expf(2.f * x);
  return 1.f - 2.f / (e + 1.f);
}
__device__ __forceinline__ float sigf(float x){
  return 1.f / (1.f + __expf(-x));
}
__device__ __forceinline__ float wsum(float v){
  #pragma unroll
  for (int o = 32; o > 0; o >>= 1) v += __shfl_xor(v, o, 64);
  return v;
}
__device__ __forceinline__ float wmaxr(float v){
  #pragma unroll
  for (int o = 32; o > 0; o >>= 1) v = fmaxf(v, __shfl_xor(v, o, 64));
  return v;
}

// 2-level grid barrier: 32 padded sub-counters (8 blocks each), wave 0 polls
// all 32 lines in parallel. All 256 blocks resident (1 block/CU by LDS).
__device__ __forceinline__ void gbar2(unsigned int* sub, unsigned int bk,
                                      int blk, int tid){
  __syncthreads();
  if (tid < 64){
    if (tid == 0){
      __threadfence();
      atomicAdd(sub + (unsigned)(blk >> 3) * 16u, 1u);
    }
    const unsigned int tgt = 8u * bk;
    for (;;){
      unsigned int v = tgt;
      if (tid < 32)
        v = __hip_atomic_load(sub + (unsigned)tid * 16u,
                              __ATOMIC_RELAXED, __HIP_MEMORY_SCOPE_AGENT);
      if (__all(v >= tgt)) break;
      __builtin_amdgcn_s_sleep(1);
    }
    if (tid == 0) __threadfence();
  }
  __syncthreads();
}

// ---------------- fp32 -> bf16 convert ----------------
__global__ void cvtk(const float* __restrict__ src, unsigned short* __restrict__ dst, int n){
  int i = blockIdx.x * blockDim.x + threadIdx.x;
  const int stride = gridDim.x * blockDim.x;
  for (; i < n; i += stride) dst[i] = f2b(src[i]);
}

// fp32 -> (hi, lo) bf16 Dekker split
__global__ void splitk(const float* __restrict__ src, unsigned short* __restrict__ hi,
                       unsigned short* __restrict__ lo, int n){
  int i = blockIdx.x * blockDim.x + threadIdx.x;
  const int stride = gridDim.x * blockDim.x;
  for (; i < n; i += stride){
    const float x = src[i];
    const unsigned short h = f2b(x);
    hi[i] = h;
    lo[i] = f2b(x - b2f((short)h));
  }
}

// bias_g[dir][j] = bih[j] + bhh[j]
__global__ void biask(const float* bihf, const float* bhhf,
                      const float* bihb, const float* bhhb, float* bg){
  int i = blockIdx.x * blockDim.x + threadIdx.x;
  if (i < G4) bg[i] = bihf[i] + bhhf[i];
  else if (i < 2 * G4) bg[i] = bihb[i - G4] + bhhb[i - G4];
}

// out[b][t][c] = bias_c (logit contributions are atomically accumulated later)
__global__ void outinit(float* out, const float* parab, const float* chapb){
  const int i = blockIdx.x * blockDim.x + threadIdx.x;
  if (i < Bz * Tz * 8){
    const int c = i & 7;
    out[i] = (c < 5) ? parab[c] : chapb[c - 5];
  }
}

// ---------------- enc_proj GEMM (split-bf16, fp32-accurate) ----------------
// ep32 = embeds @ enc_W^T + enc_b.  M=16384, N=512, K=768.
__global__ __launch_bounds__(256, 1) void encgemm(
    const float* __restrict__ embf,
    const unsigned short* __restrict__ wenchi, const unsigned short* __restrict__ wenclo,
    const float* __restrict__ encb, float* __restrict__ ep32)
{
  const int lane = threadIdx.x & 63, wvv = threadIdx.x >> 6;
  const int mt = blockIdx.x * 4 + wvv;
  const int m0 = mt * 16;
  const int n = lane & 15, quad = lane >> 4;
  f32x4 acc[32];
  #pragma unroll
  for (int i = 0; i < 32; ++i) acc[i] = (f32x4){0.f, 0.f, 0.f, 0.f};
  const float* ar = embf + ((size_t)(m0 + n)) * Ez;
  for (int kk = 0; kk < 24; ++kk){
    const int k = kk * 32 + quad * 8;
    const f32x4 a0 = *(const f32x4*)(ar + k);
    const f32x4 a1 = *(const f32x4*)(ar + k + 4);
    short8 ah, al;
    #pragma unroll
    for (int j = 0; j < 4; ++j){
      unsigned short h0 = f2b(a0[j]);
      ah[j] = (short)h0; al[j] = (short)f2b(a0[j] - b2f((short)h0));
      unsigned short h1 = f2b(a1[j]);
      ah[4 + j] = (short)h1; al[4 + j] = (short)f2b(a1[j] - b2f((short)h1));
    }
    #pragma unroll
    for (int nt = 0; nt < 32; ++nt){
      const size_t bo = ((size_t)(nt * 16 + n)) * Ez + k;
      const short8 bh = *(const short8*)(wenchi + bo);
      const short8 bl = *(const short8*)(wenclo + bo);
      acc[nt] = __builtin_amdgcn_mfma_f32_16x16x32_bf16(ah, bh, acc[nt], 0, 0, 0);
      acc[nt] = __builtin_amdgcn_mfma_f32_16x16x32_bf16(ah, bl, acc[nt], 0, 0, 0);
      acc[nt] = __builtin_amdgcn_mfma_f32_16x16x32_bf16(al, bh, acc[nt], 0, 0, 0);
    }
  }
  #pragma unroll
  for (int nt = 0; nt < 32; ++nt){
    const int colg = nt * 16 + n;
    const float bb = encb[colg];
    #pragma unroll
    for (int r = 0; r < 4; ++r){
      const int row = m0 + quad * 4 + r;
      ep32[(size_t)row * Hz + colg] = acc[nt][r] + bb;
    }
  }
}

// ---------------- persistent scan kernel ----------------
__global__ __launch_bounds__(1024) void scan_kernel(
    unsigned int* sub, unsigned int* grp,
    float* h32, float* cstate,
    unsigned short* amathi, unsigned short* amatlo, float* decw,
    float* pctx, float* pstat,
    const float* __restrict__ biasg,
    const float* __restrict__ embf, const unsigned short* __restrict__ emb16,
    const float* __restrict__ ep32,
    const unsigned short* __restrict__ wihhi, const unsigned short* __restrict__ wihlo,
    const unsigned short* __restrict__ whhhi, const unsigned short* __restrict__ whhlo,
    const float* __restrict__ decW, const float* __restrict__ decbias,
    const float* __restrict__ vvec,
    const float* __restrict__ paraW, const float* __restrict__ chapW,
    float* __restrict__ out)
{
  __shared__ float eps_lds[64 * 512];   // 128 KB: this block's enc_proj slice
  __shared__ float red[1024];
  __shared__ float scs[2][64];
  __shared__ float pw[2][64];
  __shared__ float fac[2][8];
  __shared__ float gateval[512];

  const int blk = blockIdx.x;
  const int tid = threadIdx.x;
  const int lane = tid & 63, wv = tid >> 6;

  const int a_dir = blk >> 7, a_s4 = blk & 127;   // phase A & D roles
  const int b_b = blk >> 3, b_q = blk & 7;        // phase B role (batch, t-slice)
  const int t0 = b_q * 64;

  // ---- preload this block's ep slice into LDS (stays for all 512 steps) ----
  for (int i = tid; i < 8192; i += 1024){
    const int row = i >> 7;
    const int c4 = (i & 127) << 2;
    *(f32x4*)&eps_lds[row * 512 + c4] =
        *(const f32x4*)(ep32 + ((size_t)(b_b * Tz + t0 + row)) * Hz + c4);
  }
  const f32x4 v0 = *(const f32x4*)(vvec + 8 * lane);
  const f32x4 v1 = *(const f32x4*)(vvec + 8 * lane + 4);

  unsigned int bk = 0;

  for (int s = 0; s < NSTEP; ++s){
    // ============ Phase A: dec = h @ dec_W^T + dec_b (fp32); publish h ============
    {
      const int o = tid >> 3, ks = tid & 7;
      const int ab = o >> 2, au = o & 3;
      const int col = a_s4 * 4 + au;
      const float* hr = h32 + ((size_t)(a_dir * Bz + ab)) * Hz + ks * 64;
      const float* wr = decW + (size_t)col * Hz + ks * 64;
      float acc = 0.f;
      #pragma unroll
      for (int k2 = 0; k2 < 64; k2 += 4){
        const f32x4 hv = *(const f32x4*)(hr + k2);
        const f32x4 wv4 = *(const f32x4*)(wr + k2);
        acc += hv[0] * wv4[0] + hv[1] * wv4[1] + hv[2] * wv4[2] + hv[3] * wv4[3];
      }
      red[tid] = acc;
      __syncthreads();
      if (tid < 128){
        const int b2 = tid >> 2, u2 = tid & 3;
        const int col2 = a_s4 * 4 + u2;
        float ssum = 0.f;
        #pragma unroll
        for (int j = 0; j < 8; ++j) ssum += red[tid * 8 + j];
        decw[(a_dir * Bz + b2) * Hz + col2] = ssum + decbias[col2];
        const float hval = h32[((size_t)(a_dir * Bz + b2)) * Hz + col2];
        const unsigned short hh = f2b(hval);
        const size_t ai = ((size_t)(a_dir * Bz + b2)) * KAM + 1536 + col2;
        amathi[ai] = hh;
        amatlo[ai] = f2b(hval - b2f((short)hh));
      }
    }
    ++bk; gbar2(sub, bk, blk, tid);

    // ============ Phase B: attention for (b_b, t-slice), both dirs ============
    {
      const int b = b_b, q = b_q;
      const f32x4 df0 = *(const f32x4*)(decw + ((size_t)(0 * Bz + b)) * Hz + 8 * lane);
      const f32x4 df1 = *(const f32x4*)(decw + ((size_t)(0 * Bz + b)) * Hz + 8 * lane + 4);
      const f32x4 db0 = *(const f32x4*)(decw + ((size_t)(1 * Bz + b)) * Hz + 8 * lane);
      const f32x4 db1 = *(const f32x4*)(decw + ((size_t)(1 * Bz + b)) * Hz + 8 * lane + 4);
      #pragma unroll 1
      for (int i = 0; i < 4; ++i){
        const int tl = wv * 4 + i;
        const f32x4 e0 = *(const f32x4*)&eps_lds[tl * 512 + 8 * lane];
        const f32x4 e1 = *(const f32x4*)&eps_lds[tl * 512 + 8 * lane + 4];
        float sf = 0.f, sb = 0.f;
        #pragma unroll
        for (int j = 0; j < 4; ++j){
          sf += v0[j] * fast_tanh(e0[j] + df0[j]);
          sb += v0[j] * fast_tanh(e0[j] + db0[j]);
          sf += v1[j] * fast_tanh(e1[j] + df1[j]);
          sb += v1[j] * fast_tanh(e1[j] + db1[j]);
        }
        sf = wsum(sf); sb = wsum(sb);
        if (lane == 0){ scs[0][tl] = sf; scs[1][tl] = sb; }
      }
      __syncthreads();
      if (wv < 2){
        const float sv = scs[wv][lane];
        const float m = wmaxr(sv);
        const float p = __expf(sv - m);
        const float l = wsum(p);
        pw[wv][lane] = p;
        if (lane == 0){
          pstat[(((wv * Bz) + b) * 8 + q) * 2 + 0] = m;
          pstat[(((wv * Bz) + b) * 8 + q) * 2 + 1] = l;
        }
      }
      __syncthreads();
      // partial ctx: wave wv accumulates embed-cols [wv*48, wv*48+48)
      if (lane < 48){
        const int e = wv * 48 + lane;
        const unsigned short* eb = emb16 + ((size_t)(b * Tz + t0)) * Ez + e;
        float aF = 0.f, aB = 0.f;
        #pragma unroll 4
        for (int t = 0; t < 64; ++t){
          const float x = b2f((short)eb[(size_t)t * Ez]);
          aF += pw[0][t] * x;
          aB += pw[1][t] * x;
        }
        pctx[((size_t)(0 * Bz + b) * 8 + q) * Ez + e] = aF;
        pctx[((size_t)(1 * Bz + b) * 8 + q) * Ez + e] = aB;
      }
      __syncthreads();
      // group sync: all 8 t-slice blocks of batch b
      if (tid == 0){
        __threadfence();
        atomicAdd(grp + b * 16, 1u);
        const unsigned int tgt = 8u * (unsigned)(s + 1);
        while (__hip_atomic_load(grp + b * 16, __ATOMIC_RELAXED, __HIP_MEMORY_SCOPE_AGENT) < tgt)
          __builtin_amdgcn_s_sleep(1);
        __threadfence();
      }
      __syncthreads();
      if (tid < 2){
        const int dir = tid;
        float mq[8], lq[8], M = -1e30f;
        #pragma unroll
        for (int qq = 0; qq < 8; ++qq){
          mq[qq] = pstat[(((dir * Bz) + b) * 8 + qq) * 2 + 0];
          lq[qq] = pstat[(((dir * Bz) + b) * 8 + qq) * 2 + 1];
          M = fmaxf(M, mq[qq]);
        }
        float L = 0.f;
        #pragma unroll
        for (int qq = 0; qq < 8; ++qq) L += lq[qq] * __expf(mq[qq] - M);
        const float invL = 1.f / L;
        #pragma unroll
        for (int qq = 0; qq < 8; ++qq) fac[dir][qq] = __expf(mq[qq] - M) * invL;
      }
      __syncthreads();
      // combine: this block finalizes ctx cols [q*96, q*96+96) for both dirs,
      // and stages x_t cols [q*96, q*96+96) (fp32 -> hi/lo split)
      if (tid < 192){
        const int dir = tid / 96;
        const int e = q * 96 + (tid % 96);
        float ssum = 0.f;
        #pragma unroll
        for (int qq = 0; qq < 8; ++qq)
          ssum += pctx[((size_t)(dir * Bz + b) * 8 + qq) * Ez + e] * fac[dir][qq];
        const unsigned short hh = f2b(ssum);
        const size_t ai = ((size_t)(dir * Bz + b)) * KAM + e;
        amathi[ai] = hh;
        amatlo[ai] = f2b(ssum - b2f((short)hh));
      } else if (tid >= 512 && tid < 704){
        const int dir = (tid - 512) / 96;
        const int e = q * 96 + ((tid - 512) % 96);
        const int ts = dir ? (Tz - 1 - s) : s;
        const float xv = embf[((size_t)(b * Tz + ts)) * Ez + e];
        const unsigned short hh = f2b(xv);
        const size_t ai = ((size_t)(dir * Bz + b)) * KAM + 768 + e;
        amathi[ai] = hh;
        amatlo[ai] = f2b(xv - b2f((short)hh));
      }
    }
    ++bk; gbar2(sub, bk, blk, tid);

    // ============ Phase D: gates via split-bf16 MFMA + pointwise LSTM ============
    {
      const int dir = a_dir;
      const int n = lane & 15, quad = lane >> 4;
      const int colbase = a_s4 * 4;
      const int coln = ((n >> 2) * 512) + colbase + (n & 3);
      if (tid < 512) gateval[tid] = 0.f;
      __syncthreads();
      f32x4 C0 = {0.f, 0.f, 0.f, 0.f}, C1 = {0.f, 0.f, 0.f, 0.f};
      const size_t arow0 = ((size_t)(dir * Bz) + n) * KAM;
      const size_t arow1 = arow0 + (size_t)16 * KAM;
      const int k0 = wv * 128;
      #pragma unroll
      for (int kk = 0; kk < 4; ++kk){
        const int k = k0 + kk * 32 + quad * 8;
        const short8 A0h = *(const short8*)(amathi + arow0 + k);
        const short8 A0l = *(const short8*)(amatlo + arow0 + k);
        const short8 A1h = *(const short8*)(amathi + arow1 + k);
        const short8 A1l = *(const short8*)(amatlo + arow1 + k);
        const unsigned short* bhp;
        const unsigned short* blp;
        if (k < 1536){
          const size_t o2 = ((size_t)(dir * G4) + coln) * 1536 + k;
          bhp = wihhi + o2; blp = wihlo + o2;
        } else {
          const size_t o2 = ((size_t)(dir * G4) + coln) * 512 + (k - 1536);
          bhp = whhhi + o2; blp = whhlo + o2;
        }
        const short8 Bh = *(const short8*)bhp;
        const short8 Bl = *(const short8*)blp;
        C0 = __builtin_amdgcn_mfma_f32_16x16x32_bf16(A0h, Bh, C0, 0, 0, 0);
        C0 = __builtin_amdgcn_mfma_f32_16x16x32_bf16(A0h, Bl, C0, 0, 0, 0);
        C0 = __builtin_amdgcn_mfma_f32_16x16x32_bf16(A0l, Bh, C0, 0, 0, 0);
        C1 = __builtin_amdgcn_mfma_f32_16x16x32_bf16(A1h, Bh, C1, 0, 0, 0);
        C1 = __builtin_amdgcn_mfma_f32_16x16x32_bf16(A1h, Bl, C1, 0, 0, 0);
        C1 = __builtin_amdgcn_mfma_f32_16x16x32_bf16(A1l, Bh, C1, 0, 0, 0);
      }
      #pragma unroll
      for (int r = 0; r < 4; ++r){
        unsafeAtomicAdd(&gateval[(quad * 4 + r) * 16 + n], C0[r]);
        unsafeAtomicAdd(&gateval[(16 + quad * 4 + r) * 16 + n], C1[r]);
      }
      __syncthreads();
      if (tid < 128){
        const int gb = tid >> 2, u = tid & 3;
        const int jh = colbase + u;
        const float gi = gateval[gb * 16 + u]      + biasg[dir * G4 + jh];
        const float gf = gateval[gb * 16 + 4 + u]  + biasg[dir * G4 + 512 + jh];
        const float gg = gateval[gb * 16 + 8 + u]  + biasg[dir * G4 + 1024 + jh];
        const float go = gateval[gb * 16 + 12 + u] + biasg[dir * G4 + 1536 + jh];
        float* cs = cstate + ((size_t)(dir * Bz + gb)) * Hz + jh;
        const float cold = *cs;
        const float cnew = sigf(gf) * cold + sigf(gi) * fast_tanh(gg);
        const float hval = sigf(go) * fast_tanh(cnew);
        *cs = cnew;
        h32[((size_t)(dir * Bz + gb)) * Hz + jh] = hval;
        // fused output projection: logit contributions via fp32 atomics
        const int ts = dir ? (Tz - 1 - s) : s;
        const int kk2 = dir * Hz + jh;
        float pc[8];
        #pragma unroll
        for (int c = 0; c < 8; ++c){
          const float wcoef = (c < 5) ? paraW[c * 1024 + kk2]
                                      : chapW[(c - 5) * 1024 + kk2];
          float t1 = hval * wcoef;
          t1 += __shfl_xor(t1, 1, 64);
          t1 += __shfl_xor(t1, 2, 64);
          pc[c] = t1;
        }
        if (u == 0){
          float* orow = out + ((size_t)(gb * Tz + ts)) * 8;
          #pragma unroll
          for (int c = 0; c < 8; ++c) unsafeAtomicAdd(orow + c, pc[c]);
        }
      }
    }
    ++bk; gbar2(sub, bk, blk, tid);
  }
}

extern "C" void kernel_launch(void* const* d_in, const int* in_sizes, int n_in,
                              void* d_out, int out_size, void* d_ws, size_t ws_size,
                              hipStream_t stream) {
  (void)in_sizes; (void)n_in; (void)out_size; (void)ws_size;
  const float* emb    = (const float*)d_in[0];
  const float* Wih_f  = (const float*)d_in[1];
  const float* Whh_f  = (const float*)d_in[2];
  const float* bih_f  = (const float*)d_in[3];
  const float* bhh_f  = (const float*)d_in[4];
  const float* Wih_b  = (const float*)d_in[5];
  const float* Whh_b  = (const float*)d_in[6];
  const float* bih_b  = (const float*)d_in[7];
  const float* bhh_b  = (const float*)d_in[8];
  const float* enc_W  = (const float*)d_in[9];
  const float* enc_b  = (const float*)d_in[10];
  const float* dec_W  = (const float*)d_in[11];
  const float* dec_b  = (const float*)d_in[12];
  const float* vvec   = (const float*)d_in[13];
  const float* paraW  = (const float*)d_in[14];
  const float* parab  = (const float*)d_in[15];
  const float* chapW  = (const float*)d_in[16];
  const float* chapb  = (const float*)d_in[17];
  float* out = (float*)d_out;

  uint8_t* w = (uint8_t*)d_ws;
  unsigned int* sub  = (unsigned int*)(w + OFF_SUB);
  unsigned int* grp  = (unsigned int*)(w + OFF_GRP);
  float* h32    = (float*)(w + OFF_H32);
  float* cstate = (float*)(w + OFF_CST);
  unsigned short* amathi = (unsigned short*)(w + OFF_AMATH);
  unsigned short* amatlo = (unsigned short*)(w + OFF_AMATL);
  float* decw   = (float*)(w + OFF_DEC);
  float* pctx   = (float*)(w + OFF_PCTX);
  float* pstat  = (float*)(w + OFF_PSTAT);
  float* biasg  = (float*)(w + OFF_BIASG);
  unsigned short* emb16  = (unsigned short*)(w + OFF_EMB16);
  float* ep32   = (float*)(w + OFF_EP32);
  unsigned short* wihhi = (unsigned short*)(w + OFF_WIHHI);
  unsigned short* wihlo = (unsigned short*)(w + OFF_WIHLO);
  unsigned short* whhhi = (unsigned short*)(w + OFF_WHHHI);
  unsigned short* whhlo = (unsigned short*)(w + OFF_WHHLO);
  unsigned short* wenchi = (unsigned short*)(w + OFF_WENCHI);
  unsigned short* wenclo = (unsigned short*)(w + OFF_WENCLO);

  // zero control/state region (barrier counters, group flags, h, c)
  hipMemsetAsync(d_ws, 0, CTRL_BYTES, stream);

  // weight splits + converts
  splitk<<<1024, 256, 0, stream>>>(Wih_f, wihhi,                wihlo,                G4 * 2 * Ez);
  splitk<<<1024, 256, 0, stream>>>(Wih_b, wihhi + G4 * 2 * Ez,  wihlo + G4 * 2 * Ez,  G4 * 2 * Ez);
  splitk<<<512,  256, 0, stream>>>(Whh_f, whhhi,                whhlo,                G4 * Hz);
  splitk<<<512,  256, 0, stream>>>(Whh_b, whhhi + G4 * Hz,      whhlo + G4 * Hz,      G4 * Hz);
  splitk<<<256,  256, 0, stream>>>(enc_W, wenchi,               wenclo,               Hz * Ez);
  cvtk<<<1024, 256, 0, stream>>>(emb, emb16, Bz * Tz * Ez);
  biask<<<16, 256, 0, stream>>>(bih_f, bhh_f, bih_b, bhh_b, biasg);

  // enc_proj (fp32-accurate split-bf16 MFMA)
  encgemm<<<256, 256, 0, stream>>>(emb, wenchi, wenclo, enc_b, ep32);

  // out = bias (logits accumulate atomically during the scan)
  outinit<<<512, 256, 0, stream>>>(out, parab, chapb);

  // persistent bidirectional attention-LSTM scan (fused output projection)
  scan_kernel<<<NBLK, 1024, 0, stream>>>(
      sub, grp, h32, cstate, amathi, amatlo, decw, pctx, pstat, biasg,
      emb, emb16, ep32, wihhi, wihlo, whhhi, whhlo,
      dec_W, dec_b, vvec, paraW, chapW, out);
}

// Round 3
// 43097.604 us; speedup vs baseline: 1.5252x; 1.5252x over previous
//
#include <hip/hip_runtime.h>
#include <stdint.h>

// Problem sizes
#define Bz 32
#define Tz 512
#define Ez 768
#define Hz 512
#define G4 2048      // 4*H
#define KAM 2048     // A-matrix K: [ctx(768) | x_t(768) | h(512)]
#define NBLK 256
#define NSTEP 512

typedef __attribute__((ext_vector_type(8))) short short8;
typedef __attribute__((ext_vector_type(4))) float f32x4;

// ---------------- ws layout (bytes) ----------------
#define OFF_SUB    0u            // 32 sub-barrier counters, 64B padded
#define OFF_GRP    2048u         // 32 group counters
#define OFF_HPK    4096u         // 2*32*512 u32 (bf16 hi|lo packed) = 131072
#define CTRL_BYTES 135168u       // memset-0 region: sub, grp, hpk
#define OFF_AMATH  135168u       // 64*2048 bf16 = 262144
#define OFF_AMATL  397312u       // 262144
#define OFF_DEC    659456u       // 2*32*512 f32 = 131072
#define OFF_PCTX   790528u       // 2*32*8*768 f32 = 1572864
#define OFF_PSTAT  2363392u      // 2*32*8*2 f32 = 4096
#define OFF_BIASG  2367488u      // 2*2048 f32 = 16384
#define OFF_EMB16  2383872u      // 32*512*768 bf16 = 25165824
#define OFF_EP32   27549696u     // 32*512*512 f32 = 33554432
#define OFF_WIH    61104128u     // 2*2048*1536 bf16 = 12582912
#define OFF_WHH    73687040u     // 2*2048*512 bf16 = 4194304
// wenc hi/lo alias the scan-only amat/dec region (encgemm finishes first)
#define OFF_WENCHI OFF_AMATH
#define OFF_WENCLO (OFF_AMATH + 786432u)
#define WS_NEEDED  77881344u     // ~74.3 MiB

__device__ __forceinline__ float b2f(short s){
  union { unsigned int u; float f; } w;
  w.u = ((unsigned int)(unsigned short)s) << 16;
  return w.f;
}
__device__ __forceinline__ unsigned short f2b(float f){
  union { float f; unsigned int u; } w; w.f = f;
  unsigned int u = w.u;
  return (unsigned short)((u + 0x7fffu + ((u >> 16) & 1u)) >> 16);
}
__device__ __forceinline__ float unpk(unsigned int v){
  return b2f((short)(v >> 16)) + b2f((short)(v & 0xffffu));
}
__device__ __forceinline__ unsigned int pk(float x){
  const unsigned short h = f2b(x);
  const unsigned short l = f2b(x - b2f((short)h));
  return ((unsigned int)h << 16) | (unsigned int)l;
}
__device__ __forceinline__ float fast_tanh(float x){
  float e = __expf(2.f * x);
  return 1.f - 2.f / (e + 1.f);
}
__device__ __forceinline__ float sigf(float x){
  return 1.f / (1.f + __expf(-x));
}
__device__ __forceinline__ float wsum(float v){
  #pragma unroll
  for (int o = 32; o > 0; o >>= 1) v += __shfl_xor(v, o, 64);
  return v;
}
__device__ __forceinline__ float wmaxr(float v){
  #pragma unroll
  for (int o = 32; o > 0; o >>= 1) v = fmaxf(v, __shfl_xor(v, o, 64));
  return v;
}

// relaxed agent-scope atomic access (sc-flagged, no cache invalidation)
__device__ __forceinline__ unsigned int ald32(const unsigned int* p){
  return __hip_atomic_load(p, __ATOMIC_RELAXED, __HIP_MEMORY_SCOPE_AGENT);
}
__device__ __forceinline__ float ald32f(const float* p){
  return __hip_atomic_load(p, __ATOMIC_RELAXED, __HIP_MEMORY_SCOPE_AGENT);
}
__device__ __forceinline__ unsigned long long ald64(const unsigned long long* p){
  return __hip_atomic_load(p, __ATOMIC_RELAXED, __HIP_MEMORY_SCOPE_AGENT);
}
__device__ __forceinline__ void ast32(unsigned int* p, unsigned int v){
  __hip_atomic_store(p, v, __ATOMIC_RELAXED, __HIP_MEMORY_SCOPE_AGENT);
}
__device__ __forceinline__ void ast32f(float* p, float v){
  __hip_atomic_store(p, v, __ATOMIC_RELAXED, __HIP_MEMORY_SCOPE_AGENT);
}
__device__ __forceinline__ short8 ald8s(const unsigned short* p){
  union { unsigned long long u[2]; short8 s; } w;
  const unsigned long long* q = (const unsigned long long*)p;
  w.u[0] = ald64(q);
  w.u[1] = ald64(q + 1);
  return w.s;
}

// Grid barrier: 32 padded sub-counters (8 blocks each), wave 0 polls all 32 in
// parallel. Fence-free: __syncthreads drains vmcnt per wave before s_barrier,
// so all sc-stores are complete before the arrival RMW.
__device__ __forceinline__ void gbar2(unsigned int* sub, unsigned int bk,
                                      int blk, int tid){
  __syncthreads();
  if (tid < 64){
    if (tid == 0)
      __hip_atomic_fetch_add(sub + (unsigned)(blk >> 3) * 16u, 1u,
                             __ATOMIC_RELAXED, __HIP_MEMORY_SCOPE_AGENT);
    const unsigned int tgt = 8u * bk;
    for (;;){
      unsigned int v = tgt;
      if (tid < 32)
        v = __hip_atomic_load(sub + (unsigned)tid * 16u,
                              __ATOMIC_RELAXED, __HIP_MEMORY_SCOPE_AGENT);
      if (__all(v >= tgt)) break;
      __builtin_amdgcn_s_sleep(1);
    }
  }
  __syncthreads();
}

// ---------------- fp32 -> bf16 convert ----------------
__global__ void cvtk(const float* __restrict__ src, unsigned short* __restrict__ dst, int n){
  int i = blockIdx.x * blockDim.x + threadIdx.x;
  const int stride = gridDim.x * blockDim.x;
  for (; i < n; i += stride) dst[i] = f2b(src[i]);
}

// fp32 -> (hi, lo) bf16 Dekker split
__global__ void splitk(const float* __restrict__ src, unsigned short* __restrict__ hi,
                       unsigned short* __restrict__ lo, int n){
  int i = blockIdx.x * blockDim.x + threadIdx.x;
  const int stride = gridDim.x * blockDim.x;
  for (; i < n; i += stride){
    const float x = src[i];
    const unsigned short h = f2b(x);
    hi[i] = h;
    lo[i] = f2b(x - b2f((short)h));
  }
}

// bias_g[dir][j] = bih[j] + bhh[j]
__global__ void biask(const float* bihf, const float* bhhf,
                      const float* bihb, const float* bhhb, float* bg){
  int i = blockIdx.x * blockDim.x + threadIdx.x;
  if (i < G4) bg[i] = bihf[i] + bhhf[i];
  else if (i < 2 * G4) bg[i] = bihb[i - G4] + bhhb[i - G4];
}

// out[b][t][c] = bias_c (logit contributions accumulate atomically in the scan)
__global__ void outinit(float* out, const float* parab, const float* chapb){
  const int i = blockIdx.x * blockDim.x + threadIdx.x;
  if (i < Bz * Tz * 8){
    const int c = i & 7;
    out[i] = (c < 5) ? parab[c] : chapb[c - 5];
  }
}

// ---------------- enc_proj GEMM (split-bf16, fp32-accurate) ----------------
__global__ __launch_bounds__(256, 1) void encgemm(
    const float* __restrict__ embf,
    const unsigned short* __restrict__ wenchi, const unsigned short* __restrict__ wenclo,
    const float* __restrict__ encb, float* __restrict__ ep32)
{
  const int lane = threadIdx.x & 63, wvv = threadIdx.x >> 6;
  const int mt = blockIdx.x * 4 + wvv;
  const int m0 = mt * 16;
  const int n = lane & 15, quad = lane >> 4;
  f32x4 acc[32];
  #pragma unroll
  for (int i = 0; i < 32; ++i) acc[i] = (f32x4){0.f, 0.f, 0.f, 0.f};
  const float* ar = embf + ((size_t)(m0 + n)) * Ez;
  for (int kk = 0; kk < 24; ++kk){
    const int k = kk * 32 + quad * 8;
    const f32x4 a0 = *(const f32x4*)(ar + k);
    const f32x4 a1 = *(const f32x4*)(ar + k + 4);
    short8 ah, al;
    #pragma unroll
    for (int j = 0; j < 4; ++j){
      unsigned short h0 = f2b(a0[j]);
      ah[j] = (short)h0; al[j] = (short)f2b(a0[j] - b2f((short)h0));
      unsigned short h1 = f2b(a1[j]);
      ah[4 + j] = (short)h1; al[4 + j] = (short)f2b(a1[j] - b2f((short)h1));
    }
    #pragma unroll
    for (int nt = 0; nt < 32; ++nt){
      const size_t bo = ((size_t)(nt * 16 + n)) * Ez + k;
      const short8 bh = *(const short8*)(wenchi + bo);
      const short8 bl = *(const short8*)(wenclo + bo);
      acc[nt] = __builtin_amdgcn_mfma_f32_16x16x32_bf16(ah, bh, acc[nt], 0, 0, 0);
      acc[nt] = __builtin_amdgcn_mfma_f32_16x16x32_bf16(ah, bl, acc[nt], 0, 0, 0);
      acc[nt] = __builtin_amdgcn_mfma_f32_16x16x32_bf16(al, bh, acc[nt], 0, 0, 0);
    }
  }
  #pragma unroll
  for (int nt = 0; nt < 32; ++nt){
    const int colg = nt * 16 + n;
    const float bb = encb[colg];
    #pragma unroll
    for (int r = 0; r < 4; ++r){
      const int row = m0 + quad * 4 + r;
      ep32[(size_t)row * Hz + colg] = acc[nt][r] + bb;
    }
  }
}

// ---------------- persistent scan kernel ----------------
__global__ __launch_bounds__(1024) void scan_kernel(
    unsigned int* sub, unsigned int* grp,
    unsigned int* hpk,
    unsigned short* amathi, unsigned short* amatlo, float* decw,
    float* pctx, float* pstat,
    const float* __restrict__ biasg,
    const float* __restrict__ embf, const unsigned short* __restrict__ emb16,
    const float* __restrict__ ep32,
    const unsigned short* __restrict__ wih16, const unsigned short* __restrict__ whh16,
    const float* __restrict__ decW, const float* __restrict__ decbias,
    const float* __restrict__ vvec,
    const float* __restrict__ paraW, const float* __restrict__ chapW,
    float* __restrict__ out)
{
  __shared__ float eps_lds[64 * 512];   // 128 KB enc_proj slice, resident all steps
  __shared__ float red[4096];           // 16 KB phase-A reduce
  __shared__ float decs[1024];          // dec for this block's batch, both dirs
  __shared__ float scs[2][64];
  __shared__ float pw[2][64];
  __shared__ float fac[2][8];
  __shared__ float gateval[512];

  const int blk = blockIdx.x;
  const int tid = threadIdx.x;
  const int lane = tid & 63, wv = tid >> 6;

  const int a_dir = blk >> 7, a_s4 = blk & 127;   // phase A & D roles
  const int b_b = blk >> 3, b_q = blk & 7;        // phase B role (batch, t-slice)
  const int t0 = b_q * 64;

  // ---- preload ep slice into LDS (resident for all 512 steps) ----
  for (int i = tid; i < 8192; i += 1024){
    const int row = i >> 7;
    const int c4 = (i & 127) << 2;
    *(f32x4*)&eps_lds[row * 512 + c4] =
        *(const f32x4*)(ep32 + ((size_t)(b_b * Tz + t0 + row)) * Hz + c4);
  }
  const f32x4 v0 = *(const f32x4*)(vvec + 8 * lane);
  const f32x4 v1 = *(const f32x4*)(vvec + 8 * lane + 4);

  // ---- pin phase-D B-weight fragments in registers (same 128B every step) ----
  const int dn = lane & 15, dquad = lane >> 4;
  const int colbase = a_s4 * 4;
  const int coln = ((dn >> 2) * 512) + colbase + (dn & 3);
  short8 Bfrag[4];
  #pragma unroll
  for (int kk = 0; kk < 4; ++kk){
    const int k = wv * 128 + kk * 32 + dquad * 8;
    Bfrag[kk] = (k < 1536)
      ? *(const short8*)(wih16 + ((size_t)(a_dir * G4) + coln) * 1536 + k)
      : *(const short8*)(whh16 + ((size_t)(a_dir * G4) + coln) * 512 + (k - 1536));
  }
  // ---- pin pointwise/output-projection constants (tid<128 lanes) ----
  const int p_gb = tid >> 2, p_u = tid & 3;
  const int p_jh = colbase + p_u;
  float wc[8], bgi = 0.f, bgf = 0.f, bgg = 0.f, bgo = 0.f;
  float creg = 0.f;
  if (tid < 128){
    bgi = biasg[a_dir * G4 + p_jh];
    bgf = biasg[a_dir * G4 + 512 + p_jh];
    bgg = biasg[a_dir * G4 + 1024 + p_jh];
    bgo = biasg[a_dir * G4 + 1536 + p_jh];
    const int kk2 = a_dir * Hz + p_jh;
    #pragma unroll
    for (int c = 0; c < 8; ++c)
      wc[c] = (c < 5) ? paraW[c * 1024 + kk2] : chapW[(c - 5) * 1024 + kk2];
  }

  unsigned int bk = 0;

  for (int s = 0; s < NSTEP; ++s){
    // ============ Phase A: dec = h @ dec_W^T + dec_b (fp32); publish h ============
    {
      const int ab = tid >> 5, ks4 = tid & 31;
      const int kb = ks4 * 16;
      const unsigned long long* hq =
          (const unsigned long long*)(hpk + (((size_t)(a_dir * Bz + ab)) << 9) + kb);
      float hv[16];
      #pragma unroll
      for (int j = 0; j < 8; ++j){
        const unsigned long long w2 = ald64(hq + j);
        hv[2 * j]     = unpk((unsigned int)w2);
        hv[2 * j + 1] = unpk((unsigned int)(w2 >> 32));
      }
      #pragma unroll
      for (int au = 0; au < 4; ++au){
        const float* wr = decW + ((size_t)(a_s4 * 4 + au)) * Hz + kb;
        float acc = 0.f;
        #pragma unroll
        for (int j = 0; j < 16; ++j) acc += hv[j] * wr[j];
        red[(ab * 4 + au) * 32 + ks4] = acc;
      }
      __syncthreads();
      if (tid < 128){
        const int b2 = tid >> 2, u2 = tid & 3;
        const int col2 = a_s4 * 4 + u2;
        float ssum = 0.f;
        #pragma unroll
        for (int j = 0; j < 32; ++j) ssum += red[tid * 32 + j];
        ast32f(decw + ((size_t)(a_dir * Bz + b2)) * Hz + col2, ssum + decbias[col2]);
      }
      if (tid < 64){
        const int b3 = tid >> 1, pr = tid & 1;
        const int col = a_s4 * 4 + pr * 2;
        const unsigned int w0 = ald32(hpk + ((size_t)(a_dir * Bz + b3)) * Hz + col);
        const unsigned int w1 = ald32(hpk + ((size_t)(a_dir * Bz + b3)) * Hz + col + 1);
        const unsigned wi = (((size_t)(a_dir * Bz + b3)) * KAM + 1536 + col) >> 1;
        ast32(((unsigned int*)amathi) + wi, (w0 >> 16) | (w1 & 0xffff0000u));
        ast32(((unsigned int*)amatlo) + wi, (w0 & 0xffffu) | ((w1 & 0xffffu) << 16));
      }
    }
    ++bk; gbar2(sub, bk, blk, tid);

    // ============ Phase B: attention for (b_b, t-slice), both dirs ============
    {
      const int b = b_b, q = b_q;
      // stage dec (both dirs, this batch) into LDS: one sc-load per thread
      {
        const int dir = tid >> 9, col = tid & 511;
        decs[tid] = ald32f(decw + ((size_t)(dir * Bz + b)) * Hz + col);
      }
      __syncthreads();
      const f32x4 df0 = *(const f32x4*)&decs[8 * lane];
      const f32x4 df1 = *(const f32x4*)&decs[8 * lane + 4];
      const f32x4 db0 = *(const f32x4*)&decs[512 + 8 * lane];
      const f32x4 db1 = *(const f32x4*)&decs[512 + 8 * lane + 4];
      #pragma unroll 1
      for (int i = 0; i < 4; ++i){
        const int tl = wv * 4 + i;
        const f32x4 e0 = *(const f32x4*)&eps_lds[tl * 512 + 8 * lane];
        const f32x4 e1 = *(const f32x4*)&eps_lds[tl * 512 + 8 * lane + 4];
        float sf = 0.f, sb = 0.f;
        #pragma unroll
        for (int j = 0; j < 4; ++j){
          sf += v0[j] * fast_tanh(e0[j] + df0[j]);
          sb += v0[j] * fast_tanh(e0[j] + db0[j]);
          sf += v1[j] * fast_tanh(e1[j] + df1[j]);
          sb += v1[j] * fast_tanh(e1[j] + db1[j]);
        }
        sf = wsum(sf); sb = wsum(sb);
        if (lane == 0){ scs[0][tl] = sf; scs[1][tl] = sb; }
      }
      __syncthreads();
      if (wv < 2){
        const float sv = scs[wv][lane];
        const float m = wmaxr(sv);
        const float p = __expf(sv - m);
        const float l = wsum(p);
        pw[wv][lane] = p;
        if (lane == 0){
          ast32f(pstat + (((wv * Bz) + b) * 8 + q) * 2 + 0, m);
          ast32f(pstat + (((wv * Bz) + b) * 8 + q) * 2 + 1, l);
        }
      }
      __syncthreads();
      // partial ctx: wave wv covers embed-cols [wv*48, wv*48+48)
      if (lane < 48){
        const int e = wv * 48 + lane;
        const unsigned short* eb = emb16 + ((size_t)(b * Tz + t0)) * Ez + e;
        float aF = 0.f, aB = 0.f;
        #pragma unroll 8
        for (int t = 0; t < 64; ++t){
          const float x = b2f((short)eb[(size_t)t * Ez]);
          aF += pw[0][t] * x;
          aB += pw[1][t] * x;
        }
        ast32f(pctx + ((size_t)(0 * Bz + b) * 8 + q) * Ez + e, aF);
        ast32f(pctx + ((size_t)(1 * Bz + b) * 8 + q) * Ez + e, aB);
      }
      __syncthreads();
      // group sync across the 8 t-slice blocks of batch b
      if (tid == 0){
        __hip_atomic_fetch_add(grp + b * 16, 1u,
                               __ATOMIC_RELAXED, __HIP_MEMORY_SCOPE_AGENT);
        const unsigned int tgt = 8u * (unsigned)(s + 1);
        while (__hip_atomic_load(grp + b * 16, __ATOMIC_RELAXED,
                                 __HIP_MEMORY_SCOPE_AGENT) < tgt)
          __builtin_amdgcn_s_sleep(1);
      }
      __syncthreads();
      if (tid < 2){
        const int dir = tid;
        float mq[8], lq[8], M = -1e30f;
        #pragma unroll
        for (int qq = 0; qq < 8; ++qq){
          mq[qq] = ald32f(pstat + (((dir * Bz) + b) * 8 + qq) * 2 + 0);
          lq[qq] = ald32f(pstat + (((dir * Bz) + b) * 8 + qq) * 2 + 1);
          M = fmaxf(M, mq[qq]);
        }
        float L = 0.f;
        #pragma unroll
        for (int qq = 0; qq < 8; ++qq) L += lq[qq] * __expf(mq[qq] - M);
        const float invL = 1.f / L;
        #pragma unroll
        for (int qq = 0; qq < 8; ++qq) fac[dir][qq] = __expf(mq[qq] - M) * invL;
      }
      __syncthreads();
      // combine ctx cols [q*96, q*96+96) for both dirs (2 cols/thread);
      // stage x_t cols (fp32 -> hi/lo split)
      if (tid < 96){
        const int dir = tid / 48, p = tid % 48;
        const int e = q * 96 + 2 * p;
        float s0 = 0.f, s1 = 0.f;
        #pragma unroll
        for (int qq = 0; qq < 8; ++qq){
          const float fq = fac[dir][qq];
          const float* pb = pctx + ((size_t)(dir * Bz + b) * 8 + qq) * Ez + e;
          s0 += ald32f(pb) * fq;
          s1 += ald32f(pb + 1) * fq;
        }
        const unsigned int u0 = pk(s0), u1 = pk(s1);
        const unsigned wi = (((size_t)(dir * Bz + b)) * KAM + e) >> 1;
        ast32(((unsigned int*)amathi) + wi, (u0 >> 16) | (u1 & 0xffff0000u));
        ast32(((unsigned int*)amatlo) + wi, (u0 & 0xffffu) | ((u1 & 0xffffu) << 16));
      } else if (tid >= 512 && tid < 608){
        const int i2 = tid - 512;
        const int dir = i2 / 48, p = i2 % 48;
        const int e = q * 96 + 2 * p;
        const int ts = dir ? (Tz - 1 - s) : s;
        const float x0 = embf[((size_t)(b * Tz + ts)) * Ez + e];
        const float x1 = embf[((size_t)(b * Tz + ts)) * Ez + e + 1];
        const unsigned int u0 = pk(x0), u1 = pk(x1);
        const unsigned wi = (((size_t)(dir * Bz + b)) * KAM + 768 + e) >> 1;
        ast32(((unsigned int*)amathi) + wi, (u0 >> 16) | (u1 & 0xffff0000u));
        ast32(((unsigned int*)amatlo) + wi, (u0 & 0xffffu) | ((u1 & 0xffffu) << 16));
      }
    }
    ++bk; gbar2(sub, bk, blk, tid);

    // ============ Phase D: gates via split-bf16 MFMA + pointwise LSTM ============
    {
      const int dir = a_dir;
      if (tid < 512) gateval[tid] = 0.f;
      __syncthreads();
      f32x4 C0 = {0.f, 0.f, 0.f, 0.f}, C1 = {0.f, 0.f, 0.f, 0.f};
      const size_t arow0 = ((size_t)(dir * Bz) + dn) * KAM;
      const size_t arow1 = arow0 + (size_t)16 * KAM;
      #pragma unroll
      for (int kk = 0; kk < 4; ++kk){
        const int k = wv * 128 + kk * 32 + dquad * 8;
        const short8 A0h = ald8s(amathi + arow0 + k);
        const short8 A0l = ald8s(amatlo + arow0 + k);
        const short8 A1h = ald8s(amathi + arow1 + k);
        const short8 A1l = ald8s(amatlo + arow1 + k);
        C0 = __builtin_amdgcn_mfma_f32_16x16x32_bf16(A0h, Bfrag[kk], C0, 0, 0, 0);
        C0 = __builtin_amdgcn_mfma_f32_16x16x32_bf16(A0l, Bfrag[kk], C0, 0, 0, 0);
        C1 = __builtin_amdgcn_mfma_f32_16x16x32_bf16(A1h, Bfrag[kk], C1, 0, 0, 0);
        C1 = __builtin_amdgcn_mfma_f32_16x16x32_bf16(A1l, Bfrag[kk], C1, 0, 0, 0);
      }
      #pragma unroll
      for (int r = 0; r < 4; ++r){
        unsafeAtomicAdd(&gateval[(dquad * 4 + r) * 16 + dn], C0[r]);
        unsafeAtomicAdd(&gateval[(16 + dquad * 4 + r) * 16 + dn], C1[r]);
      }
      __syncthreads();
      if (tid < 128){
        const float gi = gateval[p_gb * 16 + p_u]      + bgi;
        const float gf = gateval[p_gb * 16 + 4 + p_u]  + bgf;
        const float gg = gateval[p_gb * 16 + 8 + p_u]  + bgg;
        const float go = gateval[p_gb * 16 + 12 + p_u] + bgo;
        const float cnew = sigf(gf) * creg + sigf(gi) * fast_tanh(gg);
        const float hval = sigf(go) * fast_tanh(cnew);
        creg = cnew;
        ast32(hpk + ((size_t)(dir * Bz + p_gb)) * Hz + p_jh, pk(hval));
        // fused output projection: logit contributions via fp32 atomics
        const int ts = dir ? (Tz - 1 - s) : s;
        float pc[8];
        #pragma unroll
        for (int c = 0; c < 8; ++c){
          float t1 = hval * wc[c];
          t1 += __shfl_xor(t1, 1, 64);
          t1 += __shfl_xor(t1, 2, 64);
          pc[c] = t1;
        }
        if (p_u == 0){
          float* orow = out + ((size_t)(p_gb * Tz + ts)) * 8;
          #pragma unroll
          for (int c = 0; c < 8; ++c) unsafeAtomicAdd(orow + c, pc[c]);
        }
      }
    }
    ++bk; gbar2(sub, bk, blk, tid);
  }
}

extern "C" void kernel_launch(void* const* d_in, const int* in_sizes, int n_in,
                              void* d_out, int out_size, void* d_ws, size_t ws_size,
                              hipStream_t stream) {
  (void)in_sizes; (void)n_in; (void)out_size; (void)ws_size;
  const float* emb    = (const float*)d_in[0];
  const float* Wih_f  = (const float*)d_in[1];
  const float* Whh_f  = (const float*)d_in[2];
  const float* bih_f  = (const float*)d_in[3];
  const float* bhh_f  = (const float*)d_in[4];
  const float* Wih_b  = (const float*)d_in[5];
  const float* Whh_b  = (const float*)d_in[6];
  const float* bih_b  = (const float*)d_in[7];
  const float* bhh_b  = (const float*)d_in[8];
  const float* enc_W  = (const float*)d_in[9];
  const float* enc_b  = (const float*)d_in[10];
  const float* dec_W  = (const float*)d_in[11];
  const float* dec_b  = (const float*)d_in[12];
  const float* vvec   = (const float*)d_in[13];
  const float* paraW  = (const float*)d_in[14];
  const float* parab  = (const float*)d_in[15];
  const float* chapW  = (const float*)d_in[16];
  const float* chapb  = (const float*)d_in[17];
  float* out = (float*)d_out;

  uint8_t* w = (uint8_t*)d_ws;
  unsigned int* sub  = (unsigned int*)(w + OFF_SUB);
  unsigned int* grp  = (unsigned int*)(w + OFF_GRP);
  unsigned int* hpk  = (unsigned int*)(w + OFF_HPK);
  unsigned short* amathi = (unsigned short*)(w + OFF_AMATH);
  unsigned short* amatlo = (unsigned short*)(w + OFF_AMATL);
  float* decw   = (float*)(w + OFF_DEC);
  float* pctx   = (float*)(w + OFF_PCTX);
  float* pstat  = (float*)(w + OFF_PSTAT);
  float* biasg  = (float*)(w + OFF_BIASG);
  unsigned short* emb16  = (unsigned short*)(w + OFF_EMB16);
  float* ep32   = (float*)(w + OFF_EP32);
  unsigned short* wih16 = (unsigned short*)(w + OFF_WIH);
  unsigned short* whh16 = (unsigned short*)(w + OFF_WHH);
  unsigned short* wenchi = (unsigned short*)(w + OFF_WENCHI);
  unsigned short* wenclo = (unsigned short*)(w + OFF_WENCLO);

  // zero control/state region (barrier counters, group flags, packed h)
  hipMemsetAsync(d_ws, 0, CTRL_BYTES, stream);

  // weight converts (gate weights bf16-hi only; enc split for fp32-accurate ep)
  cvtk<<<512, 256, 0, stream>>>(Wih_f, wih16,               G4 * 2 * Ez);
  cvtk<<<512, 256, 0, stream>>>(Wih_b, wih16 + G4 * 2 * Ez, G4 * 2 * Ez);
  cvtk<<<256, 256, 0, stream>>>(Whh_f, whh16,               G4 * Hz);
  cvtk<<<256, 256, 0, stream>>>(Whh_b, whh16 + G4 * Hz,     G4 * Hz);
  splitk<<<256, 256, 0, stream>>>(enc_W, wenchi, wenclo, Hz * Ez);
  cvtk<<<1024, 256, 0, stream>>>(emb, emb16, Bz * Tz * Ez);
  biask<<<16, 256, 0, stream>>>(bih_f, bhh_f, bih_b, bhh_b, biasg);

  // enc_proj (fp32-accurate split-bf16 MFMA)
  encgemm<<<256, 256, 0, stream>>>(emb, wenchi, wenclo, enc_b, ep32);

  // out = bias (logits accumulate atomically during the scan)
  outinit<<<512, 256, 0, stream>>>(out, parab, chapb);

  // persistent bidirectional attention-LSTM scan (fused output projection)
  scan_kernel<<<NBLK, 1024, 0, stream>>>(
      sub, grp, hpk, amathi, amatlo, decw, pctx, pstat, biasg,
      emb, emb16, ep32, wih16, whh16,
      dec_W, dec_b, vvec, paraW, chapW, out);
}